// Round 12
// baseline (415.349 us; speedup 1.0000x reference)
//
#include <hip/hip_runtime.h>
#include <hip/hip_bf16.h>

typedef unsigned short u16;
typedef unsigned int   u32;
typedef unsigned long long u64;

#define SEQ 1024
#define EMB 1024
#define NH  16
#define DKH 64

// 0.125 (1/sqrt(64)) * log2(e): folded into Wq/bq so attn uses exp2 directly
#define QSCALE 0.18033688f
#define SCLAMP 43.3f

typedef __attribute__((ext_vector_type(8))) short short8;
typedef __attribute__((ext_vector_type(4))) float floatx4;

__device__ __forceinline__ float b2f(u16 u) {
  return __uint_as_float(((u32)u) << 16);
}
__device__ __forceinline__ u16 f2b(float f) {
  u32 u = __float_as_uint(f);
  u32 r = u + 0x7fffu + ((u >> 16) & 1u);   // RNE
  return (u16)(r >> 16);
}
__device__ __forceinline__ u32 pack2(float lo, float hi) {
  return (u32)f2b(lo) | ((u32)f2b(hi) << 16);
}

// ---------- probe the two 8M-element buffers ----------
// flags[0]=xIsB, flags[1]=x storage (1=bf16,0=fp32), flags[2]=mask bytes (1) vs int32 (0)
__global__ __launch_bounds__(256) void probe_inputs(const u32* __restrict__ A,
                                                    const u32* __restrict__ B,
                                                    int* __restrict__ flags) {
  __shared__ int mA, mB, mBig, xB16;
  if (threadIdx.x == 0) { mA = 0; mB = 0; mBig = 0; xB16 = 0; }
  __syncthreads();
  int la = 0, lb = 0;
  for (int i = threadIdx.x; i < 4096; i += 256) {
    if ((A[i] & 0xFEFEFEFEu) == 0) la++;
    if ((B[i] & 0xFEFEFEFEu) == 0) lb++;
  }
  atomicAdd(&mA, la); atomicAdd(&mB, lb);
  __syncthreads();
  const int xIsB = (mA > mB) ? 1 : 0;
  const u32* X = xIsB ? B : A;
  const u32* M = xIsB ? A : B;
  int big = 0, cnt = 0;
  for (int i = threadIdx.x; i < 4096; i += 256)
    if (M[i] > 1u) big = 1;
  for (int i = threadIdx.x; i < 2048; i += 256) {
    u16 v = (u16)(X[i] & 0xffffu);
    int e = (v >> 7) & 0xFF;
    if (e >= 110 && e <= 135) cnt++;
  }
  if (big) atomicOr(&mBig, 1);
  atomicAdd(&xB16, cnt);
  __syncthreads();
  if (threadIdx.x == 0) {
    flags[0] = xIsB;
    flags[1] = (xB16 > 1500) ? 1 : 0;
    flags[2] = mBig;
  }
}

// ---------- pack mask to 1 bit/element via ballot (coalesced) ----------
__global__ __launch_bounds__(256) void build_maskbits(const void* __restrict__ bigA,
                                                      const void* __restrict__ bigB,
                                                      const int* __restrict__ flags,
                                                      u32* __restrict__ out) {
  const void* mask = flags[0] ? bigA : bigB;
  const int mbyte = flags[2];
  const int t = threadIdx.x;
  const int lane = t & 63, w = t >> 6;
  const u64 base0 = (u64)blockIdx.x * 8192;
#pragma unroll 4
  for (int k = 0; k < 32; k++) {
    u64 idx = base0 + k * 256 + t;
    int v;
    if (mbyte) v = ((const unsigned char*)mask)[idx] != 0;
    else       v = ((const u32*)mask)[idx] != 0;
    u64 b = __ballot(v);
    if (lane == 0) {
      u64 wbase = (base0 + k * 256 + w * 64) >> 5;
      out[wbase]     = (u32)b;
      out[wbase + 1] = (u32)(b >> 32);
    }
  }
}

// ---------- transpose(+convert) all 4 weights in one dispatch ----------
// z=0..2 -> WtQKV rows [z*1024, z*1024+1024); z=0 pre-scaled by QSCALE. z=3 -> WtO.
__global__ __launch_bounds__(256) void transpose_convert_w4(
    const void* __restrict__ w0, const void* __restrict__ w1,
    const void* __restrict__ w2, const void* __restrict__ w3,
    u16* __restrict__ outQKV, u16* __restrict__ outO,
    const int* __restrict__ flags) {
  __shared__ float tile[32][33];
  const int z = blockIdx.z;
  const void* in = (z == 0) ? w0 : (z == 1) ? w1 : (z == 2) ? w2 : w3;
  u16* out = (z < 3) ? (outQKV + (u64)z * EMB * EMB) : outO;
  const float scale = (z == 0) ? QSCALE : 1.0f;
  const int amode = flags[1];
  const int tx = threadIdx.x & 31;
  const int ty = threadIdx.x >> 5;
  const int bx = blockIdx.x * 32, by = blockIdx.y * 32;
  if (amode) {
    const u16* inb = (const u16*)in;
#pragma unroll
    for (int r = ty; r < 32; r += 8)
      tile[r][tx] = b2f(inb[(u64)(by + r) * EMB + bx + tx]);
  } else {
    const float* inf = (const float*)in;
#pragma unroll
    for (int r = ty; r < 32; r += 8)
      tile[r][tx] = inf[(u64)(by + r) * EMB + bx + tx];
  }
  __syncthreads();
#pragma unroll
  for (int r = ty; r < 32; r += 8)
    out[(u64)(bx + r) * EMB + by + tx] = f2b(tile[tx][r] * scale);
}

// ---------- stage 4 bias vectors into fp32 ws (bq pre-scaled) ----------
__global__ __launch_bounds__(256) void convert_biases(const void* b0, const void* b1,
                                                      const void* b2, const void* b3,
                                                      float* __restrict__ out,
                                                      const int* __restrict__ flags) {
  const void* ptrs[4] = {b0, b1, b2, b3};
  const void* p = ptrs[blockIdx.x];
  const float scale = (blockIdx.x == 0) ? QSCALE : 1.0f;
  const int amode = flags[1];
  for (int i = threadIdx.x; i < 1024; i += 256) {
    float v = amode ? b2f(((const u16*)p)[i]) : ((const float*)p)[i];
    out[blockIdx.x * 1024 + i] = v * scale;
  }
}

// ---------- per-head V transpose: [s][d] -> [d][s] ----------
#define VTP 65
__global__ __launch_bounds__(256) void transpose_v(const u16* __restrict__ in,
                                                   u16* __restrict__ out) {
  __shared__ u16 tile[64 * VTP];
  const int t = threadIdx.x;
  const int s0 = blockIdx.x * 64;
  const u64 off = (u64)blockIdx.y * SEQ * DKH;
  const int row = t >> 2, c0 = (t & 3) * 16;
  const u16* ip = in + off + (u64)(s0 + row) * DKH + c0;
  *(uint4*)(&tile[row * VTP + c0])     = *(const uint4*)(ip);
  *(uint4*)(&tile[row * VTP + c0 + 8]) = *(const uint4*)(ip + 8);
  __syncthreads();
  const int d = t >> 2;
  u16 buf[16];
#pragma unroll
  for (int j = 0; j < 16; j++) buf[j] = tile[(c0 + j) * VTP + d];
  u16* op = out + off + (u64)d * SEQ + s0 + c0;
  *(uint4*)(op)     = *(uint4*)(&buf[0]);
  *(uint4*)(op + 8) = *(uint4*)(&buf[8]);
}

// ---------- fused QKV GEMM: [Q|K|V] = X @ WtQKV^T + bias  (N = 3072) ----------
// X from (XA,XB) via flags[0], dtype via flags[1]. Output: heads layout per section.
#define LDK 40
__global__ __launch_bounds__(256) void gemm_qkv(
    const void* __restrict__ XA, const void* __restrict__ XB,
    const u16* __restrict__ Wt, const float* __restrict__ bias,
    u16* __restrict__ Qg, u16* __restrict__ Kg, u16* __restrict__ Vh,
    int row0, const int* __restrict__ flags) {
  __shared__ u16 As[128 * LDK];
  __shared__ u16 Bs[128 * LDK];
  const void* X = flags[0] ? XB : XA;
  const int amode = flags[1];
  const int t = threadIdx.x;
  const int lane = t & 63;
  const int w = t >> 6;
  const int wm = w >> 1, wn = w & 1;
  const int bM = blockIdx.x * 128, bN = blockIdx.y * 128;
  const int l15 = lane & 15, l4 = lane >> 4;

  floatx4 acc[4][4];
#pragma unroll
  for (int i = 0; i < 4; i++)
#pragma unroll
    for (int j = 0; j < 4; j++)
      acc[i][j] = (floatx4){0.f, 0.f, 0.f, 0.f};

  const int sm = t >> 1;
  const int sko = (t & 1) * 16;
  const u64 xrow = (u64)(row0 + bM + sm);
  const u64 wbase = (u64)(bN + sm) * EMB + sko;

  for (int k0 = 0; k0 < EMB; k0 += 32) {
    uint4 a0, a1;
    if (amode) {
      const uint4* xa = (const uint4*)((const u16*)X + xrow * EMB + sko + k0);
      a0 = xa[0]; a1 = xa[1];
    } else {
      const float4* xf = (const float4*)((const float*)X + xrow * EMB + sko + k0);
      float4 f0 = xf[0], f1 = xf[1], f2 = xf[2], f3 = xf[3];
      a0.x = pack2(f0.x, f0.y); a0.y = pack2(f0.z, f0.w);
      a0.z = pack2(f1.x, f1.y); a0.w = pack2(f1.z, f1.w);
      a1.x = pack2(f2.x, f2.y); a1.y = pack2(f2.z, f2.w);
      a1.z = pack2(f3.x, f3.y); a1.w = pack2(f3.z, f3.w);
    }
    const uint4* wb = (const uint4*)(Wt + wbase + k0);
    uint4 b0 = wb[0], b1 = wb[1];
    uint4* da = (uint4*)(&As[sm * LDK + sko]);
    uint4* db = (uint4*)(&Bs[sm * LDK + sko]);
    da[0] = a0; da[1] = a1;
    db[0] = b0; db[1] = b1;
    __syncthreads();
    short8 af[4], bfr[4];
#pragma unroll
    for (int i = 0; i < 4; i++) {
      af[i]  = *(const short8*)(&As[(wm * 64 + i * 16 + l15) * LDK + l4 * 8]);
      bfr[i] = *(const short8*)(&Bs[(wn * 64 + i * 16 + l15) * LDK + l4 * 8]);
    }
#pragma unroll
    for (int i = 0; i < 4; i++)
#pragma unroll
      for (int j = 0; j < 4; j++)
        acc[i][j] = __builtin_amdgcn_mfma_f32_16x16x32_bf16(af[i], bfr[j], acc[i][j], 0, 0, 0);
    __syncthreads();
  }

  const int sec = bN >> 10;                 // 0=Q,1=K,2=V (block-uniform)
  u16* outp = (sec == 0) ? Qg : (sec == 1) ? Kg : Vh;
#pragma unroll
  for (int j = 0; j < 4; j++) {
    int col = bN + wn * 64 + j * 16 + l15;
    float bv = bias[col];
    int colh = col & 1023;
    int h = colh >> 6, d = colh & 63;
#pragma unroll
    for (int i = 0; i < 4; i++) {
#pragma unroll
      for (int r = 0; r < 4; r++) {
        int row = bM + wm * 64 + i * 16 + l4 * 4 + r;
        float v = acc[i][j][r] + bv;
        int n = row >> 10, s = row & 1023;
        outp[((u64)((n * NH + h) * SEQ + s)) * DKH + d] = f2b(v);
      }
    }
  }
}

// ---------- O GEMM: out_fp32 = ctx @ WtO^T + bo ----------
__global__ __launch_bounds__(256) void gemm_out(
    const u16* __restrict__ X, const u16* __restrict__ Wt,
    const float* __restrict__ bias, float* __restrict__ out) {
  __shared__ u16 As[128 * LDK];
  __shared__ u16 Bs[128 * LDK];
  const int t = threadIdx.x;
  const int lane = t & 63;
  const int w = t >> 6;
  const int wm = w >> 1, wn = w & 1;
  const int bM = blockIdx.x * 128, bN = blockIdx.y * 128;
  const int l15 = lane & 15, l4 = lane >> 4;

  floatx4 acc[4][4];
#pragma unroll
  for (int i = 0; i < 4; i++)
#pragma unroll
    for (int j = 0; j < 4; j++)
      acc[i][j] = (floatx4){0.f, 0.f, 0.f, 0.f};

  const int sm = t >> 1;
  const int sko = (t & 1) * 16;
  const u64 xbase = (u64)(bM + sm) * EMB + sko;
  const u64 wbase = (u64)(bN + sm) * EMB + sko;

  for (int k0 = 0; k0 < EMB; k0 += 32) {
    const uint4* xa = (const uint4*)(X + xbase + k0);
    const uint4* wb = (const uint4*)(Wt + wbase + k0);
    uint4 a0 = xa[0], a1 = xa[1];
    uint4 b0 = wb[0], b1 = wb[1];
    uint4* da = (uint4*)(&As[sm * LDK + sko]);
    uint4* db = (uint4*)(&Bs[sm * LDK + sko]);
    da[0] = a0; da[1] = a1;
    db[0] = b0; db[1] = b1;
    __syncthreads();
    short8 af[4], bfr[4];
#pragma unroll
    for (int i = 0; i < 4; i++) {
      af[i]  = *(const short8*)(&As[(wm * 64 + i * 16 + l15) * LDK + l4 * 8]);
      bfr[i] = *(const short8*)(&Bs[(wn * 64 + i * 16 + l15) * LDK + l4 * 8]);
    }
#pragma unroll
    for (int i = 0; i < 4; i++)
#pragma unroll
      for (int j = 0; j < 4; j++)
        acc[i][j] = __builtin_amdgcn_mfma_f32_16x16x32_bf16(af[i], bfr[j], acc[i][j], 0, 0, 0);
    __syncthreads();
  }

#pragma unroll
  for (int j = 0; j < 4; j++) {
    int col = bN + wn * 64 + j * 16 + l15;
    float bv = bias[col];
#pragma unroll
    for (int i = 0; i < 4; i++) {
#pragma unroll
      for (int r = 0; r < 4; r++) {
        int row = bM + wm * 64 + i * 16 + l4 * 4 + r;
        out[(u64)row * EMB + col] = acc[i][j][r] + bv;
      }
    }
  }
}

// ---------- MFMA flash attention, transposed-S + bitmask + exp2 ----------
#define ATS 72
__global__ __launch_bounds__(256) void attn_mfma(
    const u16* __restrict__ Q, const u16* __restrict__ K,
    const u16* __restrict__ Vt, const u32* __restrict__ maskbits,
    int b0, u16* __restrict__ ctx) {
  __shared__ u16 Ks[64 * ATS];   // [s_local][d]
  __shared__ u16 Vs[64 * ATS];   // [d][s_local]
  __shared__ u16 Ps[64 * ATS];   // [q_local][s_local]

  const int t = threadIdx.x;
  const int lane = t & 63, w = t >> 6;
  const int l15 = lane & 15, l4 = lane >> 4;
  const int bid = blockIdx.x;
  const int h = bid & 15;
  const int qt = (bid >> 4) & 15;
  const int n = bid >> 8;
  const int nh = n * NH + h;
  const int q0 = qt * 64;
  const u64 hoff = (u64)nh * SEQ * DKH;

  short8 qf0, qf1;
  {
    const u16* qp = Q + hoff + (u64)(q0 + w * 16 + l15) * DKH + l4 * 8;
    qf0 = *(const short8*)(qp);
    qf1 = *(const short8*)(qp + 32);
  }

  floatx4 o[4];
#pragma unroll
  for (int j = 0; j < 4; j++) o[j] = (floatx4){0.f, 0.f, 0.f, 0.f};
  float lsum = 0.f;

  const int srow = t >> 2, sc0 = (t & 3) * 16;
  const u64 mrow = ((u64)((b0 + n) * SEQ + q0 + w * 16 + l15)) * 32;
  const int pq = w * 16 + l15;

  for (int kc = 0; kc < SEQ; kc += 64) {
    __syncthreads();
    {
      const u16* kp = K + hoff + (u64)(kc + srow) * DKH + sc0;
      const u16* vp = Vt + hoff + (u64)srow * SEQ + kc + sc0;
      *(uint4*)(&Ks[srow * ATS + sc0])     = *(const uint4*)(kp);
      *(uint4*)(&Ks[srow * ATS + sc0 + 8]) = *(const uint4*)(kp + 8);
      *(uint4*)(&Vs[srow * ATS + sc0])     = *(const uint4*)(vp);
      *(uint4*)(&Vs[srow * ATS + sc0 + 8]) = *(const uint4*)(vp + 8);
    }
    __syncthreads();

    const u64 mbits = *(const u64*)(maskbits + mrow + (kc >> 5));

#pragma unroll
    for (int j = 0; j < 4; j++) {
      floatx4 s = (floatx4){0.f, 0.f, 0.f, 0.f};
      short8 kb0 = *(const short8*)(&Ks[(j * 16 + l15) * ATS + l4 * 8]);
      short8 kb1 = *(const short8*)(&Ks[(j * 16 + l15) * ATS + 32 + l4 * 8]);
      s = __builtin_amdgcn_mfma_f32_16x16x32_bf16(kb0, qf0, s, 0, 0, 0);
      s = __builtin_amdgcn_mfma_f32_16x16x32_bf16(kb1, qf1, s, 0, 0, 0);

      const u32 mj = (u32)(mbits >> (j * 16 + l4 * 4)) & 0xFu;
      // Q pre-scaled by 0.125*log2e -> p = exp2(s); v_exp_f32 is native exp2
      float p0 = (mj & 1u) ? 0.f : exp2f(fminf(s[0], SCLAMP));
      float p1 = (mj & 2u) ? 0.f : exp2f(fminf(s[1], SCLAMP));
      float p2 = (mj & 4u) ? 0.f : exp2f(fminf(s[2], SCLAMP));
      float p3 = (mj & 8u) ? 0.f : exp2f(fminf(s[3], SCLAMP));
      lsum += (p0 + p1) + (p2 + p3);
      __hip_bfloat162 pk01 = __float22bfloat162_rn(make_float2(p0, p1));
      __hip_bfloat162 pk23 = __float22bfloat162_rn(make_float2(p2, p3));
      uint2 pk;
      pk.x = *(u32*)&pk01;
      pk.y = *(u32*)&pk23;
      *(uint2*)(&Ps[pq * ATS + j * 16 + l4 * 4]) = pk;
    }

    short8 pa0 = *(const short8*)(&Ps[(w * 16 + l15) * ATS + l4 * 8]);
    short8 pa1 = *(const short8*)(&Ps[(w * 16 + l15) * ATS + 32 + l4 * 8]);
#pragma unroll
    for (int j = 0; j < 4; j++) {
      short8 vb0 = *(const short8*)(&Vs[(j * 16 + l15) * ATS + l4 * 8]);
      short8 vb1 = *(const short8*)(&Vs[(j * 16 + l15) * ATS + 32 + l4 * 8]);
      o[j] = __builtin_amdgcn_mfma_f32_16x16x32_bf16(pa0, vb0, o[j], 0, 0, 0);
      o[j] = __builtin_amdgcn_mfma_f32_16x16x32_bf16(pa1, vb1, o[j], 0, 0, 0);
    }
  }

  lsum += __shfl_xor(lsum, 16, 64);
  lsum += __shfl_xor(lsum, 32, 64);
  float inv = 1.0f / fmaxf(lsum, 1e-30f);

#pragma unroll
  for (int r = 0; r < 4; r++) {
    float invr = __shfl(inv, l4 * 4 + r, 64);
    int q = q0 + w * 16 + l4 * 4 + r;
    u64 base = ((u64)(n * SEQ + q)) * EMB + h * DKH + l15;
#pragma unroll
    for (int j = 0; j < 4; j++)
      ctx[base + j * 16] = f2b(o[j][r] * invr);
  }
}

extern "C" void kernel_launch(void* const* d_in, const int* in_sizes, int n_in,
                              void* d_out, int out_size, void* d_ws, size_t ws_size,
                              hipStream_t stream) {
  // Identify buffers by size class; x vs mask (same size) resolved on-device.
  int bigI[2] = {0, 1}, wI[4] = {2, 4, 6, 8}, bI[4] = {3, 5, 7, 9};
  int nb = 0, nw = 0, nbi = 0;
  for (int i = 0; i < n_in; i++) {
    if (in_sizes[i] == 8388608) { if (nb < 2) bigI[nb++] = i; }
    else if (in_sizes[i] == 1048576) { if (nw < 4) wI[nw++] = i; }
    else if (in_sizes[i] == 1024) { if (nbi < 4) bI[nbi++] = i; }
  }
  int oq = 0, ok = 1, ov = 2, oo = 3;
  if (nb == 2 && bigI[0] == 4 && bigI[1] == 9) { oq = 2; ok = 0; ov = 3; oo = 1; }

  const void* bigA = d_in[bigI[0]];
  const void* bigB = d_in[bigI[1]];
  const void* Wq = d_in[wI[oq]];
  const void* Wk = d_in[wI[ok]];
  const void* Wv = d_in[wI[ov]];
  const void* Wo = d_in[wI[oo]];
  const void* bq = d_in[bI[oq]];
  const void* bk = d_in[bI[ok]];
  const void* bv = d_in[bI[ov]];
  const void* bo = d_in[bI[oo]];

  char* ws = (char*)d_ws;
  // [0,6MB) WtQKV; [6,8MB) WtO; 8MB: biases (16KB); +16KB flags; +64KB maskbits (1MB);
  // group region at 10MB: Qg/Kg/Vh/Vt, 2MB*G each; ctx aliases Vh.
  u16* WtQKV = (u16*)ws;
  u16* WtO   = (u16*)(ws + (6ull << 20));
  float* biasf = (float*)(ws + (8ull << 20));
  int* flags = (int*)(ws + (8ull << 20) + 16384);
  u32* maskbits = (u32*)(ws + (8ull << 20) + 65536);
  char* grp = ws + (10ull << 20);

  int G = 1;
  for (int g = 8; g >= 1; g >>= 1) {
    if (ws_size >= (10ull << 20) + (u64)g * (8ull << 20)) { G = g; break; }
  }
  const u64 gsz = (u64)G * (2ull << 20);
  u16* Qg = (u16*)grp;
  u16* Kg = (u16*)(grp + gsz);
  u16* Vh = (u16*)(grp + 2 * gsz);     // V heads layout; later reused as ctx
  u16* Vt = (u16*)(grp + 3 * gsz);     // V transposed [d][s]

  dim3 tb(256);

  probe_inputs<<<dim3(1), tb, 0, stream>>>((const u32*)bigA, (const u32*)bigB, flags);
  build_maskbits<<<dim3(1024), tb, 0, stream>>>(bigA, bigB, flags, maskbits);

  transpose_convert_w4<<<dim3(32, 32, 4), tb, 0, stream>>>(Wq, Wk, Wv, Wo, WtQKV, WtO, flags);
  convert_biases<<<dim3(4), tb, 0, stream>>>(bq, bk, bv, bo, biasf, flags);

  for (int b0 = 0; b0 < 8; b0 += G) {
    int row0 = b0 * 1024;
    gemm_qkv<<<dim3(8 * G, 24), tb, 0, stream>>>(bigA, bigB, WtQKV, biasf,
                                                 Qg, Kg, Vh, row0, flags);
    transpose_v<<<dim3(16, G * 16), tb, 0, stream>>>(Vh, Vt);

    attn_mfma<<<dim3(G * 16 * 16), tb, 0, stream>>>(Qg, Kg, Vt, maskbits, b0, Vh);

    gemm_out<<<dim3(8 * G, 8), tb, 0, stream>>>(Vh, WtO, biasf + 3072,
                                                (float*)d_out + (u64)row0 * EMB);
  }
}

// Round 13
// 359.408 us; speedup vs baseline: 1.1556x; 1.1556x over previous
//
#include <hip/hip_runtime.h>
#include <hip/hip_bf16.h>

typedef unsigned short u16;
typedef unsigned int   u32;
typedef unsigned long long u64;

#define SEQ 1024
#define EMB 1024
#define NH  16
#define DKH 64

// 0.125 (1/sqrt(64)) * log2(e): folded into Wq/bq so attn uses exp2 directly
#define QSCALE 0.18033688f
#define SCLAMP 43.3f

typedef __attribute__((ext_vector_type(8))) short short8;
typedef __attribute__((ext_vector_type(4))) float floatx4;

__device__ __forceinline__ float b2f(u16 u) {
  return __uint_as_float(((u32)u) << 16);
}
__device__ __forceinline__ u16 f2b(float f) {
  u32 u = __float_as_uint(f);
  u32 r = u + 0x7fffu + ((u >> 16) & 1u);   // RNE
  return (u16)(r >> 16);
}

// async global->LDS, 16 B per lane; LDS dst = wave-uniform base + lane*16
__device__ __forceinline__ void glds16(const u16* g, u16* l) {
  __builtin_amdgcn_global_load_lds(
      (const __attribute__((address_space(1))) u32*)g,
      (__attribute__((address_space(3))) u32*)l, 16, 0, 0);
}

// ---------- probe the two 8M-element buffers ----------
// flags[0]=xIsB, flags[1]=x storage (1=bf16,0=fp32), flags[2]=mask bytes (1) vs int32 (0)
__global__ __launch_bounds__(256) void probe_inputs(const u32* __restrict__ A,
                                                    const u32* __restrict__ B,
                                                    int* __restrict__ flags) {
  __shared__ int mA, mB, mBig, xB16;
  if (threadIdx.x == 0) { mA = 0; mB = 0; mBig = 0; xB16 = 0; }
  __syncthreads();
  int la = 0, lb = 0;
  for (int i = threadIdx.x; i < 4096; i += 256) {
    if ((A[i] & 0xFEFEFEFEu) == 0) la++;
    if ((B[i] & 0xFEFEFEFEu) == 0) lb++;
  }
  atomicAdd(&mA, la); atomicAdd(&mB, lb);
  __syncthreads();
  const int xIsB = (mA > mB) ? 1 : 0;
  const u32* X = xIsB ? B : A;
  const u32* M = xIsB ? A : B;
  int big = 0, cnt = 0;
  for (int i = threadIdx.x; i < 4096; i += 256)
    if (M[i] > 1u) big = 1;
  for (int i = threadIdx.x; i < 2048; i += 256) {
    u16 v = (u16)(X[i] & 0xffffu);
    int e = (v >> 7) & 0xFF;
    if (e >= 110 && e <= 135) cnt++;
  }
  if (big) atomicOr(&mBig, 1);
  atomicAdd(&xB16, cnt);
  __syncthreads();
  if (threadIdx.x == 0) {
    flags[0] = xIsB;
    flags[1] = (xB16 > 1500) ? 1 : 0;
    flags[2] = mBig;
  }
}

// ---------- convert x to bf16 once (or copy if already bf16) ----------
__global__ __launch_bounds__(256) void convert_x(const void* __restrict__ bigA,
                                                 const void* __restrict__ bigB,
                                                 const int* __restrict__ flags,
                                                 u16* __restrict__ out) {
  const void* x = flags[0] ? bigB : bigA;
  int i = (blockIdx.x * 256 + threadIdx.x) * 4;
  if (flags[1]) {
    *(ushort4*)(out + i) = *(const ushort4*)((const u16*)x + i);
  } else {
    float4 v = *(const float4*)((const float*)x + i);
    ushort4 o;
    o.x = f2b(v.x); o.y = f2b(v.y); o.z = f2b(v.z); o.w = f2b(v.w);
    *(ushort4*)(out + i) = o;
  }
}

// ---------- pack mask to 1 bit/element via ballot (coalesced) ----------
__global__ __launch_bounds__(256) void build_maskbits(const void* __restrict__ bigA,
                                                      const void* __restrict__ bigB,
                                                      const int* __restrict__ flags,
                                                      u32* __restrict__ out) {
  const void* mask = flags[0] ? bigA : bigB;
  const int mbyte = flags[2];
  const int t = threadIdx.x;
  const int lane = t & 63, w = t >> 6;
  const u64 base0 = (u64)blockIdx.x * 8192;
#pragma unroll 4
  for (int k = 0; k < 32; k++) {
    u64 idx = base0 + k * 256 + t;
    int v;
    if (mbyte) v = ((const unsigned char*)mask)[idx] != 0;
    else       v = ((const u32*)mask)[idx] != 0;
    u64 b = __ballot(v);
    if (lane == 0) {
      u64 wbase = (base0 + k * 256 + w * 64) >> 5;
      out[wbase]     = (u32)b;
      out[wbase + 1] = (u32)(b >> 32);
    }
  }
}

// ---------- transpose(+convert) all 4 weights in one dispatch ----------
__global__ __launch_bounds__(256) void transpose_convert_w4(
    const void* __restrict__ w0, const void* __restrict__ w1,
    const void* __restrict__ w2, const void* __restrict__ w3,
    u16* __restrict__ outQKV, u16* __restrict__ outO,
    const int* __restrict__ flags) {
  __shared__ float tile[32][33];
  const int z = blockIdx.z;
  const void* in = (z == 0) ? w0 : (z == 1) ? w1 : (z == 2) ? w2 : w3;
  u16* out = (z < 3) ? (outQKV + (u64)z * EMB * EMB) : outO;
  const float scale = (z == 0) ? QSCALE : 1.0f;
  const int amode = flags[1];
  const int tx = threadIdx.x & 31;
  const int ty = threadIdx.x >> 5;
  const int bx = blockIdx.x * 32, by = blockIdx.y * 32;
  if (amode) {
    const u16* inb = (const u16*)in;
#pragma unroll
    for (int r = ty; r < 32; r += 8)
      tile[r][tx] = b2f(inb[(u64)(by + r) * EMB + bx + tx]);
  } else {
    const float* inf = (const float*)in;
#pragma unroll
    for (int r = ty; r < 32; r += 8)
      tile[r][tx] = inf[(u64)(by + r) * EMB + bx + tx];
  }
  __syncthreads();
#pragma unroll
  for (int r = ty; r < 32; r += 8)
    out[(u64)(bx + r) * EMB + by + tx] = f2b(tile[tx][r] * scale);
}

// ---------- stage 4 bias vectors into fp32 ws (bq pre-scaled) ----------
__global__ __launch_bounds__(256) void convert_biases(const void* b0, const void* b1,
                                                      const void* b2, const void* b3,
                                                      float* __restrict__ out,
                                                      const int* __restrict__ flags) {
  const void* ptrs[4] = {b0, b1, b2, b3};
  const void* p = ptrs[blockIdx.x];
  const float scale = (blockIdx.x == 0) ? QSCALE : 1.0f;
  const int amode = flags[1];
  for (int i = threadIdx.x; i < 1024; i += 256) {
    float v = amode ? b2f(((const u16*)p)[i]) : ((const float*)p)[i];
    out[blockIdx.x * 1024 + i] = v * scale;
  }
}

// ---------- per-head V transpose: [s][d] -> [d][s] ----------
#define VTP 65
__global__ __launch_bounds__(256) void transpose_v(const u16* __restrict__ in,
                                                   u16* __restrict__ out) {
  __shared__ u16 tile[64 * VTP];
  const int t = threadIdx.x;
  const int s0 = blockIdx.x * 64;
  const u64 off = (u64)blockIdx.y * SEQ * DKH;
  const int row = t >> 2, c0 = (t & 3) * 16;
  const u16* ip = in + off + (u64)(s0 + row) * DKH + c0;
  *(uint4*)(&tile[row * VTP + c0])     = *(const uint4*)(ip);
  *(uint4*)(&tile[row * VTP + c0 + 8]) = *(const uint4*)(ip + 8);
  __syncthreads();
  const int d = t >> 2;
  u16 buf[16];
#pragma unroll
  for (int j = 0; j < 16; j++) buf[j] = tile[(c0 + j) * VTP + d];
  u16* op = out + off + (u64)d * SEQ + s0 + c0;
  *(uint4*)(op)     = *(uint4*)(&buf[0]);
  *(uint4*)(op + 8) = *(uint4*)(&buf[8]);
}

// ---------- fused QKV GEMM with global_load_lds staging (bf16 X) ----------
// [Q|K|V] = xb @ WtQKV^T + bias; output heads layout per 1024-col section.
__global__ __launch_bounds__(256) void gemm_qkv(
    const u16* __restrict__ X, const u16* __restrict__ Wt,
    const float* __restrict__ bias,
    u16* __restrict__ Qg, u16* __restrict__ Kg, u16* __restrict__ Vh,
    int row0) {
  __shared__ u16 As[128 * 32];
  __shared__ u16 Bs[128 * 32];
  const int t = threadIdx.x;
  const int lane = t & 63;
  const int w4 = t >> 6;
  const int wm = w4 >> 1, wn = w4 & 1;
  const int bM = blockIdx.x * 128, bN = blockIdx.y * 128;
  const int l15 = lane & 15, l4 = lane >> 4;

  floatx4 acc[4][4];
#pragma unroll
  for (int i = 0; i < 4; i++)
#pragma unroll
    for (int j = 0; j < 4; j++)
      acc[i][j] = (floatx4){0.f, 0.f, 0.f, 0.f};

  // staging geometry: wave w covers rows [w*32, w*32+32) via 2 issues of 16 rows
  const int rb = w4 * 32 + (lane >> 2);
  const int cb = (lane & 3) * 8;
  const u16* Ap = X + (u64)(row0 + bM + rb) * EMB + cb;
  const u16* Bp = Wt + (u64)(bN + rb) * EMB + cb;
  u16* AsW = &As[(w4 * 32) * 32];
  u16* BsW = &Bs[(w4 * 32) * 32];

  for (int k0 = 0; k0 < EMB; k0 += 32) {
    __syncthreads();
    glds16(Ap + k0, AsW);
    glds16(Ap + 16 * EMB + k0, AsW + 512);
    glds16(Bp + k0, BsW);
    glds16(Bp + 16 * EMB + k0, BsW + 512);
    __syncthreads();
    short8 af[4], bfr[4];
#pragma unroll
    for (int i = 0; i < 4; i++) {
      af[i]  = *(const short8*)(&As[(wm * 64 + i * 16 + l15) * 32 + l4 * 8]);
      bfr[i] = *(const short8*)(&Bs[(wn * 64 + i * 16 + l15) * 32 + l4 * 8]);
    }
#pragma unroll
    for (int i = 0; i < 4; i++)
#pragma unroll
      for (int j = 0; j < 4; j++)
        acc[i][j] = __builtin_amdgcn_mfma_f32_16x16x32_bf16(af[i], bfr[j], acc[i][j], 0, 0, 0);
  }

  const int sec = bN >> 10;                 // 0=Q,1=K,2=V (block-uniform)
  u16* outp = (sec == 0) ? Qg : (sec == 1) ? Kg : Vh;
#pragma unroll
  for (int j = 0; j < 4; j++) {
    int col = bN + wn * 64 + j * 16 + l15;
    float bv = bias[col];
    int colh = col & 1023;
    int h = colh >> 6, d = colh & 63;
#pragma unroll
    for (int i = 0; i < 4; i++) {
#pragma unroll
      for (int r = 0; r < 4; r++) {
        int row = bM + wm * 64 + i * 16 + l4 * 4 + r;
        float v = acc[i][j][r] + bv;
        int n = row >> 10, s = row & 1023;
        outp[((u64)((n * NH + h) * SEQ + s)) * DKH + d] = f2b(v);
      }
    }
  }
}

// ---------- O GEMM with global_load_lds: out_fp32 = ctx @ WtO^T + bo ----------
__global__ __launch_bounds__(256) void gemm_out(
    const u16* __restrict__ X, const u16* __restrict__ Wt,
    const float* __restrict__ bias, float* __restrict__ out) {
  __shared__ u16 As[128 * 32];
  __shared__ u16 Bs[128 * 32];
  const int t = threadIdx.x;
  const int lane = t & 63;
  const int w4 = t >> 6;
  const int wm = w4 >> 1, wn = w4 & 1;
  const int bM = blockIdx.x * 128, bN = blockIdx.y * 128;
  const int l15 = lane & 15, l4 = lane >> 4;

  floatx4 acc[4][4];
#pragma unroll
  for (int i = 0; i < 4; i++)
#pragma unroll
    for (int j = 0; j < 4; j++)
      acc[i][j] = (floatx4){0.f, 0.f, 0.f, 0.f};

  const int rb = w4 * 32 + (lane >> 2);
  const int cb = (lane & 3) * 8;
  const u16* Ap = X + (u64)(bM + rb) * EMB + cb;
  const u16* Bp = Wt + (u64)(bN + rb) * EMB + cb;
  u16* AsW = &As[(w4 * 32) * 32];
  u16* BsW = &Bs[(w4 * 32) * 32];

  for (int k0 = 0; k0 < EMB; k0 += 32) {
    __syncthreads();
    glds16(Ap + k0, AsW);
    glds16(Ap + 16 * EMB + k0, AsW + 512);
    glds16(Bp + k0, BsW);
    glds16(Bp + 16 * EMB + k0, BsW + 512);
    __syncthreads();
    short8 af[4], bfr[4];
#pragma unroll
    for (int i = 0; i < 4; i++) {
      af[i]  = *(const short8*)(&As[(wm * 64 + i * 16 + l15) * 32 + l4 * 8]);
      bfr[i] = *(const short8*)(&Bs[(wn * 64 + i * 16 + l15) * 32 + l4 * 8]);
    }
#pragma unroll
    for (int i = 0; i < 4; i++)
#pragma unroll
      for (int j = 0; j < 4; j++)
        acc[i][j] = __builtin_amdgcn_mfma_f32_16x16x32_bf16(af[i], bfr[j], acc[i][j], 0, 0, 0);
  }

#pragma unroll
  for (int j = 0; j < 4; j++) {
    int col = bN + wn * 64 + j * 16 + l15;
    float bv = bias[col];
#pragma unroll
    for (int i = 0; i < 4; i++) {
#pragma unroll
      for (int r = 0; r < 4; r++) {
        int row = bM + wm * 64 + i * 16 + l4 * 4 + r;
        out[(u64)row * EMB + col] = acc[i][j][r] + bv;
      }
    }
  }
}

// ---------- MFMA flash attention, transposed-S + bitmask + exp2 ----------
#define ATS 72
__global__ __launch_bounds__(256) void attn_mfma(
    const u16* __restrict__ Q, const u16* __restrict__ K,
    const u16* __restrict__ Vt, const u32* __restrict__ maskbits,
    int b0, u16* __restrict__ ctx) {
  __shared__ u16 Ks[64 * ATS];   // [s_local][d]
  __shared__ u16 Vs[64 * ATS];   // [d][s_local]
  __shared__ u16 Ps[64 * ATS];   // [q_local][s_local]

  const int t = threadIdx.x;
  const int lane = t & 63, w = t >> 6;
  const int l15 = lane & 15, l4 = lane >> 4;
  const int bid = blockIdx.x;
  const int h = bid & 15;
  const int qt = (bid >> 4) & 15;
  const int n = bid >> 8;
  const int nh = n * NH + h;
  const int q0 = qt * 64;
  const u64 hoff = (u64)nh * SEQ * DKH;

  short8 qf0, qf1;
  {
    const u16* qp = Q + hoff + (u64)(q0 + w * 16 + l15) * DKH + l4 * 8;
    qf0 = *(const short8*)(qp);
    qf1 = *(const short8*)(qp + 32);
  }

  floatx4 o[4];
#pragma unroll
  for (int j = 0; j < 4; j++) o[j] = (floatx4){0.f, 0.f, 0.f, 0.f};
  float lsum = 0.f;

  const int srow = t >> 2, sc0 = (t & 3) * 16;
  const u64 mrow = ((u64)((b0 + n) * SEQ + q0 + w * 16 + l15)) * 32;
  const int pq = w * 16 + l15;

  for (int kc = 0; kc < SEQ; kc += 64) {
    __syncthreads();
    {
      const u16* kp = K + hoff + (u64)(kc + srow) * DKH + sc0;
      const u16* vp = Vt + hoff + (u64)srow * SEQ + kc + sc0;
      *(uint4*)(&Ks[srow * ATS + sc0])     = *(const uint4*)(kp);
      *(uint4*)(&Ks[srow * ATS + sc0 + 8]) = *(const uint4*)(kp + 8);
      *(uint4*)(&Vs[srow * ATS + sc0])     = *(const uint4*)(vp);
      *(uint4*)(&Vs[srow * ATS + sc0 + 8]) = *(const uint4*)(vp + 8);
    }
    __syncthreads();

    const u64 mbits = *(const u64*)(maskbits + mrow + (kc >> 5));

#pragma unroll
    for (int j = 0; j < 4; j++) {
      floatx4 s = (floatx4){0.f, 0.f, 0.f, 0.f};
      short8 kb0 = *(const short8*)(&Ks[(j * 16 + l15) * ATS + l4 * 8]);
      short8 kb1 = *(const short8*)(&Ks[(j * 16 + l15) * ATS + 32 + l4 * 8]);
      s = __builtin_amdgcn_mfma_f32_16x16x32_bf16(kb0, qf0, s, 0, 0, 0);
      s = __builtin_amdgcn_mfma_f32_16x16x32_bf16(kb1, qf1, s, 0, 0, 0);

      const u32 mj = (u32)(mbits >> (j * 16 + l4 * 4)) & 0xFu;
      float p0 = (mj & 1u) ? 0.f : exp2f(fminf(s[0], SCLAMP));
      float p1 = (mj & 2u) ? 0.f : exp2f(fminf(s[1], SCLAMP));
      float p2 = (mj & 4u) ? 0.f : exp2f(fminf(s[2], SCLAMP));
      float p3 = (mj & 8u) ? 0.f : exp2f(fminf(s[3], SCLAMP));
      lsum += (p0 + p1) + (p2 + p3);
      __hip_bfloat162 pk01 = __float22bfloat162_rn(make_float2(p0, p1));
      __hip_bfloat162 pk23 = __float22bfloat162_rn(make_float2(p2, p3));
      uint2 pk;
      pk.x = *(u32*)&pk01;
      pk.y = *(u32*)&pk23;
      *(uint2*)(&Ps[pq * ATS + j * 16 + l4 * 4]) = pk;
    }

    short8 pa0 = *(const short8*)(&Ps[(w * 16 + l15) * ATS + l4 * 8]);
    short8 pa1 = *(const short8*)(&Ps[(w * 16 + l15) * ATS + 32 + l4 * 8]);
#pragma unroll
    for (int j = 0; j < 4; j++) {
      short8 vb0 = *(const short8*)(&Vs[(j * 16 + l15) * ATS + l4 * 8]);
      short8 vb1 = *(const short8*)(&Vs[(j * 16 + l15) * ATS + 32 + l4 * 8]);
      o[j] = __builtin_amdgcn_mfma_f32_16x16x32_bf16(pa0, vb0, o[j], 0, 0, 0);
      o[j] = __builtin_amdgcn_mfma_f32_16x16x32_bf16(pa1, vb1, o[j], 0, 0, 0);
    }
  }

  lsum += __shfl_xor(lsum, 16, 64);
  lsum += __shfl_xor(lsum, 32, 64);
  float inv = 1.0f / fmaxf(lsum, 1e-30f);

#pragma unroll
  for (int r = 0; r < 4; r++) {
    float invr = __shfl(inv, l4 * 4 + r, 64);
    int q = q0 + w * 16 + l4 * 4 + r;
    u64 base = ((u64)(n * SEQ + q)) * EMB + h * DKH + l15;
#pragma unroll
    for (int j = 0; j < 4; j++)
      ctx[base + j * 16] = f2b(o[j][r] * invr);
  }
}

extern "C" void kernel_launch(void* const* d_in, const int* in_sizes, int n_in,
                              void* d_out, int out_size, void* d_ws, size_t ws_size,
                              hipStream_t stream) {
  // Identify buffers by size class; x vs mask (same size) resolved on-device.
  int bigI[2] = {0, 1}, wI[4] = {2, 4, 6, 8}, bI[4] = {3, 5, 7, 9};
  int nb = 0, nw = 0, nbi = 0;
  for (int i = 0; i < n_in; i++) {
    if (in_sizes[i] == 8388608) { if (nb < 2) bigI[nb++] = i; }
    else if (in_sizes[i] == 1048576) { if (nw < 4) wI[nw++] = i; }
    else if (in_sizes[i] == 1024) { if (nbi < 4) bI[nbi++] = i; }
  }
  int oq = 0, ok = 1, ov = 2, oo = 3;
  if (nb == 2 && bigI[0] == 4 && bigI[1] == 9) { oq = 2; ok = 0; ov = 3; oo = 1; }

  const void* bigA = d_in[bigI[0]];
  const void* bigB = d_in[bigI[1]];
  const void* Wq = d_in[wI[oq]];
  const void* Wk = d_in[wI[ok]];
  const void* Wv = d_in[wI[ov]];
  const void* Wo = d_in[wI[oo]];
  const void* bq = d_in[bI[oq]];
  const void* bk = d_in[bI[ok]];
  const void* bv = d_in[bI[ov]];
  const void* bo = d_in[bI[oo]];

  char* ws = (char*)d_ws;
  // [0,6MB) WtQKV; [6,8MB) WtO; 8MB: biases (16KB); +16KB flags; +64KB maskbits (1MB);
  // [10,26MB) xb (bf16 x); group region at 26MB: Qg/Kg/Vh/Vt, 2MB*G each; ctx aliases Vh.
  u16* WtQKV = (u16*)ws;
  u16* WtO   = (u16*)(ws + (6ull << 20));
  float* biasf = (float*)(ws + (8ull << 20));
  int* flags = (int*)(ws + (8ull << 20) + 16384);
  u32* maskbits = (u32*)(ws + (8ull << 20) + 65536);
  u16* xb = (u16*)(ws + (10ull << 20));
  char* grp = ws + (26ull << 20);

  int G = 1;
  for (int g = 8; g >= 1; g >>= 1) {
    if (ws_size >= (26ull << 20) + (u64)g * (8ull << 20)) { G = g; break; }
  }
  const u64 gsz = (u64)G * (2ull << 20);
  u16* Qg = (u16*)grp;
  u16* Kg = (u16*)(grp + gsz);
  u16* Vh = (u16*)(grp + 2 * gsz);     // V heads layout; later reused as ctx
  u16* Vt = (u16*)(grp + 3 * gsz);     // V transposed [d][s]

  dim3 tb(256);

  probe_inputs<<<dim3(1), tb, 0, stream>>>((const u32*)bigA, (const u32*)bigB, flags);
  convert_x<<<dim3(8192), tb, 0, stream>>>(bigA, bigB, flags, xb);
  build_maskbits<<<dim3(1024), tb, 0, stream>>>(bigA, bigB, flags, maskbits);

  transpose_convert_w4<<<dim3(32, 32, 4), tb, 0, stream>>>(Wq, Wk, Wv, Wo, WtQKV, WtO, flags);
  convert_biases<<<dim3(4), tb, 0, stream>>>(bq, bk, bv, bo, biasf, flags);

  for (int b0 = 0; b0 < 8; b0 += G) {
    int row0 = b0 * 1024;
    gemm_qkv<<<dim3(8 * G, 24), tb, 0, stream>>>(xb, WtQKV, biasf, Qg, Kg, Vh, row0);
    transpose_v<<<dim3(16, G * 16), tb, 0, stream>>>(Vh, Vt);

    attn_mfma<<<dim3(G * 16 * 16), tb, 0, stream>>>(Qg, Kg, Vt, maskbits, b0, Vh);

    gemm_out<<<dim3(8 * G, 8), tb, 0, stream>>>(Vh, WtO, biasf + 3072,
                                                (float*)d_out + (u64)row0 * EMB);
  }
}